// Round 1
// baseline (156.389 us; speedup 1.0000x reference)
//
#include <hip/hip_runtime.h>
#include <hip/hip_bf16.h>

// Problem constants
#define B_SZ   4096
#define IN_SZ  256
#define U_SZ   128
#define G_SZ   1000
#define LW_SZ  64
#define LB_SZ  32

// GEMM tiling: out[B, U] = A[B, K] * Wf[K, U],  K = LW*IN = 16384
// A[b, k] = zw[b, k>>8] * x[b, k&255]  (generated on the fly)
#define BM     128
#define BK     64
#define KSPL   16
#define KLEN   ((LW_SZ * IN_SZ) / KSPL)   // 1024 K per block
#define NSTEP  (KLEN / BK)                 // 16 steps
#define LPB    (LW_SZ / KSPL)              // 4 l-values per block

typedef __attribute__((ext_vector_type(8))) short bf16x8;
typedef __attribute__((ext_vector_type(4))) float f32x4;

__device__ __forceinline__ ushort f2bf(float f) {
    // round-to-nearest-even f32 -> bf16 (inputs are finite; no NaN handling needed)
    unsigned u = __float_as_uint(f);
    u += 0x7fffu + ((u >> 16) & 1u);
    return (ushort)(u >> 16);
}

__device__ __forceinline__ float softplus_f(float v) {
    // log1p(exp(v)), numerically stable
    return fmaxf(v, 0.0f) + log1pf(__expf(-fabsf(v)));
}

// ---------------------------------------------------------------------------
// Bias kernel: out[b,u] = sum_l (zb_mu[g,l] + softplus(zb_sigma[g,l])*eps_b[b,l]) * Bf[l,u]
// Runs FIRST: it fully overwrites d_out (resets poison), then GEMM atomically adds.
// ---------------------------------------------------------------------------
__global__ __launch_bounds__(256) void fmd_bias(
    const float* __restrict__ eps_b,
    const float* __restrict__ zb_mu,
    const float* __restrict__ zb_sigma,
    const float* __restrict__ Bf,
    const int*   __restrict__ gid,
    float*       __restrict__ out)
{
    const int half = threadIdx.x >> 7;           // 2 rows per block
    const int u    = threadIdx.x & 127;
    const int b    = blockIdx.x * 2 + half;

    __shared__ float zb[2][LB_SZ];
    if (u < LB_SZ) {
        int g = gid[b];
        float sg = softplus_f(zb_sigma[g * LB_SZ + u]);
        zb[half][u] = zb_mu[g * LB_SZ + u] + sg * eps_b[b * LB_SZ + u];
    }
    __syncthreads();

    float acc = 0.0f;
    #pragma unroll
    for (int l = 0; l < LB_SZ; ++l)
        acc += zb[half][l] * Bf[l * U_SZ + u];
    out[b * U_SZ + u] = acc;
}

// ---------------------------------------------------------------------------
// Fused GEMM: grid = (B/BM) * KSPL = 32*16 = 512 blocks, 256 threads (4 waves).
// Wave tile 64x64 (4x4 fragments of 16x16x32 bf16 MFMA).
// Block bid: ks = bid & 15 (K-split), mt = bid >> 4 (M-tile).
// bid%8 == ks%8 -> same-K-slice blocks share an XCD L2 (slice = 512 KB fp32).
// ---------------------------------------------------------------------------
__global__ __launch_bounds__(256, 2) void fmd_gemm(
    const float* __restrict__ x,
    const float* __restrict__ eps_w,
    const float* __restrict__ zw_mu,
    const float* __restrict__ zw_sigma,
    const float* __restrict__ Wf,
    const int*   __restrict__ gid,
    float*       __restrict__ out)
{
    const int tid  = threadIdx.x;
    const int lane = tid & 63;
    const int wid  = tid >> 6;
    const int wr   = wid >> 1;          // wave row (0..1)
    const int wc   = wid & 1;           // wave col (0..1)
    const int bid  = blockIdx.x;
    const int ks   = bid & (KSPL - 1);
    const int mt   = bid >> 4;
    const int m0   = mt * BM;

    // LDS: XOR-swizzled (byte ^= (row&7)<<4  ==  short-idx ^= (row&7)<<3)
    __shared__ short As[BM * BK];       // As[r][k], k-contiguous, 16 KB
    __shared__ short Bs[U_SZ * BK];     // Bs[u][k] (Wf transposed), 16 KB
    __shared__ float zw_s[BM][LPB];     // per-row sampled weights, 2 KB

    // --- sample zw for this block's rows & l-range ---
    for (int it = tid; it < BM * LPB; it += 256) {
        int r = it >> 2, lloc = it & 3;
        int b = m0 + r;
        int g = gid[b];
        int l = ks * LPB + lloc;
        float sg = softplus_f(zw_sigma[g * LW_SZ + l]);
        zw_s[r][lloc] = zw_mu[g * LW_SZ + l] + sg * eps_w[b * LW_SZ + l];
    }

    f32x4 acc[4][4];
    #pragma unroll
    for (int m = 0; m < 4; ++m)
        #pragma unroll
        for (int n = 0; n < 4; ++n)
            acc[m][n] = (f32x4){0.f, 0.f, 0.f, 0.f};

    for (int s = 0; s < NSTEP; ++s) {
        __syncthreads();   // prev step's reads done (also covers zw_s at s=0)
        const int li = s >> 2;             // local l index (0..3)
        const int i0 = (s & 3) * BK;       // x column offset
        const int k0 = ks * KLEN + s * BK; // global k base

        // --- stage A: As[r][c] = zw[r]*x[b0+r][i0+c], 128x64 floats ---
        #pragma unroll
        for (int it = 0; it < 8; ++it) {
            int idx = it * 256 + tid;      // 0..2047 float4 slots
            int r = idx >> 4, c4 = idx & 15;
            float4 xv = *reinterpret_cast<const float4*>(&x[(m0 + r) * IN_SZ + i0 + c4 * 4]);
            float zw = zw_s[r][li];
            ushort h0 = f2bf(xv.x * zw), h1 = f2bf(xv.y * zw);
            ushort h2 = f2bf(xv.z * zw), h3 = f2bf(xv.w * zw);
            unsigned long long pw = (unsigned long long)h0
                                  | ((unsigned long long)h1 << 16)
                                  | ((unsigned long long)h2 << 32)
                                  | ((unsigned long long)h3 << 48);
            int si = (r * BK + c4 * 4) ^ ((r & 7) << 3);
            *reinterpret_cast<unsigned long long*>(&As[si]) = pw;
        }
        // --- stage B (transpose Wf slice): Bs[u][kk] = Wf[k0+kk][u] ---
        #pragma unroll
        for (int it = 0; it < 4; ++it) {
            int idx = it * 256 + tid;      // 0..1023 slots of 8 k's
            int u = idx & 127, kg = idx >> 7;
            union { ushort h[8]; bf16x8 v; } pk;
            #pragma unroll
            for (int j = 0; j < 8; ++j)
                pk.h[j] = f2bf(Wf[(k0 + kg * 8 + j) * U_SZ + u]);
            int si = (u * BK + kg * 8) ^ ((u & 7) << 3);
            *reinterpret_cast<bf16x8*>(&Bs[si]) = pk.v;
        }
        __syncthreads();

        // --- MFMA: 2 x (K=32) sub-steps ---
        #pragma unroll
        for (int kb = 0; kb < 2; ++kb) {
            bf16x8 af[4], bfr[4];
            #pragma unroll
            for (int m = 0; m < 4; ++m) {
                int row = wr * 64 + m * 16 + (lane & 15);
                int si = (row * BK + kb * 32 + (lane >> 4) * 8) ^ ((row & 7) << 3);
                af[m] = *reinterpret_cast<const bf16x8*>(&As[si]);
            }
            #pragma unroll
            for (int n = 0; n < 4; ++n) {
                int rowu = wc * 64 + n * 16 + (lane & 15);
                int si = (rowu * BK + kb * 32 + (lane >> 4) * 8) ^ ((rowu & 7) << 3);
                bfr[n] = *reinterpret_cast<const bf16x8*>(&Bs[si]);
            }
            #pragma unroll
            for (int m = 0; m < 4; ++m)
                #pragma unroll
                for (int n = 0; n < 4; ++n)
                    acc[m][n] = __builtin_amdgcn_mfma_f32_16x16x32_bf16(af[m], bfr[n], acc[m][n], 0, 0, 0);
        }
    }

    // --- epilogue: C/D layout col=lane&15, row=(lane>>4)*4+j; split-K via atomics ---
    #pragma unroll
    for (int m = 0; m < 4; ++m) {
        int row0 = m0 + wr * 64 + m * 16 + ((lane >> 4) << 2);
        #pragma unroll
        for (int n = 0; n < 4; ++n) {
            int col = wc * 64 + n * 16 + (lane & 15);
            #pragma unroll
            for (int j = 0; j < 4; ++j)
                atomicAdd(&out[(row0 + j) * U_SZ + col], acc[m][n][j]);
        }
    }
}

extern "C" void kernel_launch(void* const* d_in, const int* in_sizes, int n_in,
                              void* d_out, int out_size, void* d_ws, size_t ws_size,
                              hipStream_t stream) {
    const float* x        = (const float*)d_in[0];
    const float* eps_w    = (const float*)d_in[1];
    const float* eps_b    = (const float*)d_in[2];
    const float* zw_mu    = (const float*)d_in[3];
    const float* zw_sigma = (const float*)d_in[4];
    const float* Wf       = (const float*)d_in[5];
    const float* zb_mu    = (const float*)d_in[6];
    const float* zb_sigma = (const float*)d_in[7];
    const float* Bf       = (const float*)d_in[8];
    const int*   gid      = (const int*)d_in[9];
    float* out = (float*)d_out;

    // bias kernel fully overwrites out (deterministic reset), then GEMM accumulates
    fmd_bias<<<B_SZ / 2, 256, 0, stream>>>(eps_b, zb_mu, zb_sigma, Bf, gid, out);
    fmd_gemm<<<(B_SZ / BM) * KSPL, 256, 0, stream>>>(x, eps_w, zw_mu, zw_sigma, Wf, gid, out);
}

// Round 2
// 56.343 us; speedup vs baseline: 2.7757x; 2.7757x over previous
//
#include <hip/hip_runtime.h>
#include <hip/hip_bf16.h>
#include <stdint.h>

// Problem constants
#define B_SZ   4096
#define IN_SZ  256
#define U_SZ   128
#define G_SZ   1000
#define LW_SZ  64
#define LB_SZ  32
#define K_SZ   (LW_SZ * IN_SZ)      // 16384

// GEMM tiling: out[B, U] = A[B, K] * Wf[K, U]
// A[b, k] = zw[b, k>>8] * x[b, k&255]  (generated on the fly)
#define BM     128
#define BK     64
#define KSPL   16
#define KLEN   (K_SZ / KSPL)        // 1024 K per block
#define NSTEP  (KLEN / BK)          // 16 steps
#define NTILE  (K_SZ / BK)          // 256 global k-tiles
#define CHUNK  (BK * U_SZ)          // 8192 shorts per pre-swizzled B tile

typedef __attribute__((ext_vector_type(8))) short bf16x8;
typedef __attribute__((ext_vector_type(4))) float f32x4;

typedef const void __attribute__((address_space(1)))* gas_ptr;
typedef void __attribute__((address_space(3)))* las_ptr;

__device__ __forceinline__ ushort f2bf(float f) {
    unsigned u = __float_as_uint(f);
    u += 0x7fffu + ((u >> 16) & 1u);
    return (ushort)(u >> 16);
}

__device__ __forceinline__ float softplus_f(float v) {
    return fmaxf(v, 0.0f) + log1pf(__expf(-fabsf(v)));
}

// ---------------------------------------------------------------------------
// Prep: Wf [16384 x 128] fp32  ->  wfT bf16, per 64-k tile, transposed to
// Bs[u][kk] layout WITH the XOR swizzle pre-applied, so the GEMM can stage it
// with linear-dest global_load_lds. chunk[u*64 + c] = bf16(Wf[(t*64 + (c ^ ((u&7)<<3)))*128 + u])
// ---------------------------------------------------------------------------
__global__ __launch_bounds__(256) void fmd_prep_wf(
    const float* __restrict__ Wf, short* __restrict__ wfT)
{
    const int t = blockIdx.x;          // k-tile 0..255
    const int tid = threadIdx.x;
    __shared__ float lds[64 * 132];    // [kk][u], pad 132 to break bank stride

    #pragma unroll
    for (int it = 0; it < 8; ++it) {
        int idx = it * 256 + tid;      // 2048 float4 slots
        int kk = idx >> 5, u4 = idx & 31;
        float4 v = *reinterpret_cast<const float4*>(&Wf[(t * 64 + kk) * U_SZ + u4 * 4]);
        *reinterpret_cast<float4*>(&lds[kk * 132 + u4 * 4]) = v;
    }
    __syncthreads();

    short* chunk = wfT + t * CHUNK;
    #pragma unroll
    for (int g = 0; g < 4; ++g) {
        int p = g * 2048 + tid * 8;    // linear chunk position (8 shorts)
        int u = p >> 6;
        int c = p & 63;
        int kk0 = c ^ ((u & 7) << 3);  // swizzle touches bits 3..5 only
        union { ushort h[8]; bf16x8 v; } pk;
        #pragma unroll
        for (int j = 0; j < 8; ++j)
            pk.h[j] = f2bf(lds[(kk0 + j) * 132 + u]);
        *reinterpret_cast<bf16x8*>(&chunk[p]) = pk.v;
    }
}

// ---------------------------------------------------------------------------
// Prep: zw_samp[b,l] = zw_mu[g,l] + softplus(zw_sigma[g,l]) * eps_w[b,l]
// ---------------------------------------------------------------------------
__global__ __launch_bounds__(256) void fmd_zw(
    const float* __restrict__ eps_w,
    const float* __restrict__ zw_mu,
    const float* __restrict__ zw_sigma,
    const int*   __restrict__ gid,
    float*       __restrict__ zw_samp)
{
    int idx = blockIdx.x * 256 + threadIdx.x;   // 0..262143
    int b = idx >> 6, l = idx & 63;
    int g = gid[b];
    float sg = softplus_f(zw_sigma[g * LW_SZ + l]);
    zw_samp[idx] = zw_mu[g * LW_SZ + l] + sg * eps_w[idx];
}

// ---------------------------------------------------------------------------
// Bias kernel: fully overwrites d_out (deterministic reset of poison).
// ---------------------------------------------------------------------------
__global__ __launch_bounds__(256) void fmd_bias(
    const float* __restrict__ eps_b,
    const float* __restrict__ zb_mu,
    const float* __restrict__ zb_sigma,
    const float* __restrict__ Bf,
    const int*   __restrict__ gid,
    float*       __restrict__ out)
{
    const int half = threadIdx.x >> 7;
    const int u    = threadIdx.x & 127;
    const int b    = blockIdx.x * 2 + half;

    __shared__ float zb[2][LB_SZ];
    if (u < LB_SZ) {
        int g = gid[b];
        float sg = softplus_f(zb_sigma[g * LB_SZ + u]);
        zb[half][u] = zb_mu[g * LB_SZ + u] + sg * eps_b[b * LB_SZ + u];
    }
    __syncthreads();

    float acc = 0.0f;
    #pragma unroll
    for (int l = 0; l < LB_SZ; ++l)
        acc += zb[half][l] * Bf[l * U_SZ + u];
    out[b * U_SZ + u] = acc;
}

// ---------------------------------------------------------------------------
// GEMM: grid = 32 M-tiles * KSPL = 512 blocks, 4 waves, 64x64 wave tile.
// MODE 0: store fp32 partials to ws slice [ks][B][U].  MODE 1: atomicAdd out.
// B-operand staged async via global_load_lds from pre-swizzled wfT chunks.
// ---------------------------------------------------------------------------
template<int MODE>
__global__ __launch_bounds__(256, 2) void fmd_gemm2(
    const float* __restrict__ x,
    const float* __restrict__ zw_samp,
    const short* __restrict__ wfT,
    float*       __restrict__ outp)
{
    const int tid  = threadIdx.x;
    const int lane = tid & 63;
    const int wid  = tid >> 6;
    const int wr   = wid >> 1;
    const int wc   = wid & 1;
    const int bid  = blockIdx.x;
    const int ks   = bid & (KSPL - 1);
    const int mt   = bid >> 4;
    const int m0   = mt * BM;

    __shared__ short As[BM * BK];       // 16 KB, XOR-swizzled
    __shared__ short Bs[U_SZ * BK];     // 16 KB, XOR-swizzled (via pre-swizzled src)
    __shared__ float zw_s[BM][4];

    if (tid < BM) {
        float4 z = *reinterpret_cast<const float4*>(&zw_samp[(m0 + tid) * LW_SZ + ks * 4]);
        zw_s[tid][0] = z.x; zw_s[tid][1] = z.y; zw_s[tid][2] = z.z; zw_s[tid][3] = z.w;
    }

    f32x4 acc[4][4];
    #pragma unroll
    for (int m = 0; m < 4; ++m)
        #pragma unroll
        for (int n = 0; n < 4; ++n)
            acc[m][n] = (f32x4){0.f, 0.f, 0.f, 0.f};

    for (int s = 0; s < NSTEP; ++s) {
        __syncthreads();   // prev step's LDS reads done (also covers zw_s at s=0)

        // --- stage B: async global_load_lds from pre-swizzled chunk ---
        const short* chunk = wfT + (ks * NSTEP + s) * CHUNK;
        const int bbase = wid * 2048;
        #pragma unroll
        for (int j = 0; j < 4; ++j) {
            __builtin_amdgcn_global_load_lds(
                (gas_ptr)(chunk + bbase + j * 512 + lane * 8),
                (las_ptr)(&Bs[bbase + j * 512]),
                16, 0, 0);
        }

        // --- stage A: As[r][c] = zw[r]*x[m0+r][i0+c] (overlaps B's flight) ---
        const int li = s >> 2;
        const int i0 = (s & 3) * BK;
        #pragma unroll
        for (int it = 0; it < 8; ++it) {
            int idx = it * 256 + tid;
            int r = idx >> 4, c4 = idx & 15;
            float4 xv = *reinterpret_cast<const float4*>(&x[(m0 + r) * IN_SZ + i0 + c4 * 4]);
            float zw = zw_s[r][li];
            ushort h0 = f2bf(xv.x * zw), h1 = f2bf(xv.y * zw);
            ushort h2 = f2bf(xv.z * zw), h3 = f2bf(xv.w * zw);
            unsigned long long pw = (unsigned long long)h0
                                  | ((unsigned long long)h1 << 16)
                                  | ((unsigned long long)h2 << 32)
                                  | ((unsigned long long)h3 << 48);
            int si = (r * BK + c4 * 4) ^ ((r & 7) << 3);
            *reinterpret_cast<unsigned long long*>(&As[si]) = pw;
        }
        __syncthreads();   // drains vmcnt (global_load_lds) + lgkm

        // --- MFMA ---
        #pragma unroll
        for (int kb = 0; kb < 2; ++kb) {
            bf16x8 af[4], bfr[4];
            #pragma unroll
            for (int m = 0; m < 4; ++m) {
                int row = wr * 64 + m * 16 + (lane & 15);
                int si = (row * BK + kb * 32 + (lane >> 4) * 8) ^ ((row & 7) << 3);
                af[m] = *reinterpret_cast<const bf16x8*>(&As[si]);
            }
            #pragma unroll
            for (int n = 0; n < 4; ++n) {
                int rowu = wc * 64 + n * 16 + (lane & 15);
                int si = (rowu * BK + kb * 32 + (lane >> 4) * 8) ^ ((rowu & 7) << 3);
                bfr[n] = *reinterpret_cast<const bf16x8*>(&Bs[si]);
            }
            #pragma unroll
            for (int m = 0; m < 4; ++m)
                #pragma unroll
                for (int n = 0; n < 4; ++n)
                    acc[m][n] = __builtin_amdgcn_mfma_f32_16x16x32_bf16(af[m], bfr[n], acc[m][n], 0, 0, 0);
        }
    }

    // --- epilogue ---
    float* dst = (MODE == 0) ? (outp + (size_t)ks * (B_SZ * U_SZ)) : outp;
    #pragma unroll
    for (int m = 0; m < 4; ++m) {
        int row0 = m0 + wr * 64 + m * 16 + ((lane >> 4) << 2);
        #pragma unroll
        for (int n = 0; n < 4; ++n) {
            int col = wc * 64 + n * 16 + (lane & 15);
            #pragma unroll
            for (int j = 0; j < 4; ++j) {
                if (MODE == 0)
                    dst[(row0 + j) * U_SZ + col] = acc[m][n][j];
                else
                    atomicAdd(&dst[(row0 + j) * U_SZ + col], acc[m][n][j]);
            }
        }
    }
}

// ---------------------------------------------------------------------------
// Reduce: out = bias(out) + sum_ks partial[ks]   (float4 vectorized)
// ---------------------------------------------------------------------------
__global__ __launch_bounds__(256) void fmd_reduce(
    const float* __restrict__ part, float* __restrict__ out)
{
    int i = blockIdx.x * 256 + threadIdx.x;        // float4 index, 0..131071
    const f32x4* p4 = (const f32x4*)part;
    f32x4* o4 = (f32x4*)out;
    f32x4 s = o4[i];                                // bias already there
    #pragma unroll
    for (int ks = 0; ks < KSPL; ++ks)
        s += p4[ks * (B_SZ * U_SZ / 4) + i];
    o4[i] = s;
}

// ---------------------------------------------------------------------------
// Legacy round-1 GEMM (fallback if ws_size too small for wfT+zw buffers)
// ---------------------------------------------------------------------------
__global__ __launch_bounds__(256, 2) void fmd_gemm_legacy(
    const float* __restrict__ x,
    const float* __restrict__ eps_w,
    const float* __restrict__ zw_mu,
    const float* __restrict__ zw_sigma,
    const float* __restrict__ Wf,
    const int*   __restrict__ gid,
    float*       __restrict__ out)
{
    const int tid  = threadIdx.x;
    const int lane = tid & 63;
    const int wid  = tid >> 6;
    const int wr   = wid >> 1;
    const int wc   = wid & 1;
    const int bid  = blockIdx.x;
    const int ks   = bid & (KSPL - 1);
    const int mt   = bid >> 4;
    const int m0   = mt * BM;

    __shared__ short As[BM * BK];
    __shared__ short Bs[U_SZ * BK];
    __shared__ float zw_s[BM][4];

    for (int it = tid; it < BM * 4; it += 256) {
        int r = it >> 2, lloc = it & 3;
        int b = m0 + r;
        int g = gid[b];
        int l = ks * 4 + lloc;
        float sg = softplus_f(zw_sigma[g * LW_SZ + l]);
        zw_s[r][lloc] = zw_mu[g * LW_SZ + l] + sg * eps_w[b * LW_SZ + l];
    }

    f32x4 acc[4][4];
    #pragma unroll
    for (int m = 0; m < 4; ++m)
        #pragma unroll
        for (int n = 0; n < 4; ++n)
            acc[m][n] = (f32x4){0.f, 0.f, 0.f, 0.f};

    for (int s = 0; s < NSTEP; ++s) {
        __syncthreads();
        const int li = s >> 2;
        const int i0 = (s & 3) * BK;
        const int k0 = ks * KLEN + s * BK;

        #pragma unroll
        for (int it = 0; it < 8; ++it) {
            int idx = it * 256 + tid;
            int r = idx >> 4, c4 = idx & 15;
            float4 xv = *reinterpret_cast<const float4*>(&x[(m0 + r) * IN_SZ + i0 + c4 * 4]);
            float zw = zw_s[r][li];
            ushort h0 = f2bf(xv.x * zw), h1 = f2bf(xv.y * zw);
            ushort h2 = f2bf(xv.z * zw), h3 = f2bf(xv.w * zw);
            unsigned long long pw = (unsigned long long)h0
                                  | ((unsigned long long)h1 << 16)
                                  | ((unsigned long long)h2 << 32)
                                  | ((unsigned long long)h3 << 48);
            int si = (r * BK + c4 * 4) ^ ((r & 7) << 3);
            *reinterpret_cast<unsigned long long*>(&As[si]) = pw;
        }
        #pragma unroll
        for (int it = 0; it < 4; ++it) {
            int idx = it * 256 + tid;
            int u = idx & 127, kg = idx >> 7;
            union { ushort h[8]; bf16x8 v; } pk;
            #pragma unroll
            for (int j = 0; j < 8; ++j)
                pk.h[j] = f2bf(Wf[(k0 + kg * 8 + j) * U_SZ + u]);
            int si = (u * BK + kg * 8) ^ ((u & 7) << 3);
            *reinterpret_cast<bf16x8*>(&Bs[si]) = pk.v;
        }
        __syncthreads();

        #pragma unroll
        for (int kb = 0; kb < 2; ++kb) {
            bf16x8 af[4], bfr[4];
            #pragma unroll
            for (int m = 0; m < 4; ++m) {
                int row = wr * 64 + m * 16 + (lane & 15);
                int si = (row * BK + kb * 32 + (lane >> 4) * 8) ^ ((row & 7) << 3);
                af[m] = *reinterpret_cast<const bf16x8*>(&As[si]);
            }
            #pragma unroll
            for (int n = 0; n < 4; ++n) {
                int rowu = wc * 64 + n * 16 + (lane & 15);
                int si = (rowu * BK + kb * 32 + (lane >> 4) * 8) ^ ((rowu & 7) << 3);
                bfr[n] = *reinterpret_cast<const bf16x8*>(&Bs[si]);
            }
            #pragma unroll
            for (int m = 0; m < 4; ++m)
                #pragma unroll
                for (int n = 0; n < 4; ++n)
                    acc[m][n] = __builtin_amdgcn_mfma_f32_16x16x32_bf16(af[m], bfr[n], acc[m][n], 0, 0, 0);
        }
    }

    #pragma unroll
    for (int m = 0; m < 4; ++m) {
        int row0 = m0 + wr * 64 + m * 16 + ((lane >> 4) << 2);
        #pragma unroll
        for (int n = 0; n < 4; ++n) {
            int col = wc * 64 + n * 16 + (lane & 15);
            #pragma unroll
            for (int j = 0; j < 4; ++j)
                atomicAdd(&out[(row0 + j) * U_SZ + col], acc[m][n][j]);
        }
    }
}

extern "C" void kernel_launch(void* const* d_in, const int* in_sizes, int n_in,
                              void* d_out, int out_size, void* d_ws, size_t ws_size,
                              hipStream_t stream) {
    const float* x        = (const float*)d_in[0];
    const float* eps_w    = (const float*)d_in[1];
    const float* eps_b    = (const float*)d_in[2];
    const float* zw_mu    = (const float*)d_in[3];
    const float* zw_sigma = (const float*)d_in[4];
    const float* Wf       = (const float*)d_in[5];
    const float* zb_mu    = (const float*)d_in[6];
    const float* zb_sigma = (const float*)d_in[7];
    const float* Bf       = (const float*)d_in[8];
    const int*   gid      = (const int*)d_in[9];
    float* out = (float*)d_out;

    const size_t WFT_BYTES  = (size_t)K_SZ * U_SZ * 2;          // 4 MB
    const size_t ZW_OFF     = WFT_BYTES;
    const size_t ZW_BYTES   = (size_t)B_SZ * LW_SZ * 4;         // 1 MB
    const size_t PART_OFF   = ZW_OFF + ZW_BYTES;
    const size_t PART_BYTES = (size_t)KSPL * B_SZ * U_SZ * 4;   // 32 MB

    if (ws_size >= PART_OFF + PART_BYTES) {
        short* wfT     = (short*)d_ws;
        float* zw_samp = (float*)((char*)d_ws + ZW_OFF);
        float* part    = (float*)((char*)d_ws + PART_OFF);
        fmd_prep_wf<<<NTILE, 256, 0, stream>>>(Wf, wfT);
        fmd_zw<<<(B_SZ * LW_SZ) / 256, 256, 0, stream>>>(eps_w, zw_mu, zw_sigma, gid, zw_samp);
        fmd_bias<<<B_SZ / 2, 256, 0, stream>>>(eps_b, zb_mu, zb_sigma, Bf, gid, out);
        fmd_gemm2<0><<<(B_SZ / BM) * KSPL, 256, 0, stream>>>(x, zw_samp, wfT, part);
        fmd_reduce<<<(B_SZ * U_SZ) / 1024, 256, 0, stream>>>(part, out);
    } else if (ws_size >= PART_OFF) {
        short* wfT     = (short*)d_ws;
        float* zw_samp = (float*)((char*)d_ws + ZW_OFF);
        fmd_prep_wf<<<NTILE, 256, 0, stream>>>(Wf, wfT);
        fmd_zw<<<(B_SZ * LW_SZ) / 256, 256, 0, stream>>>(eps_w, zw_mu, zw_sigma, gid, zw_samp);
        fmd_bias<<<B_SZ / 2, 256, 0, stream>>>(eps_b, zb_mu, zb_sigma, Bf, gid, out);
        fmd_gemm2<1><<<(B_SZ / BM) * KSPL, 256, 0, stream>>>(x, zw_samp, wfT, out);
    } else {
        fmd_bias<<<B_SZ / 2, 256, 0, stream>>>(eps_b, zb_mu, zb_sigma, Bf, gid, out);
        fmd_gemm_legacy<<<(B_SZ / BM) * KSPL, 256, 0, stream>>>(x, eps_w, zw_mu, zw_sigma, Wf, gid, out);
    }
}

// Round 3
// 43.957 us; speedup vs baseline: 3.5578x; 1.2818x over previous
//
#include <hip/hip_runtime.h>
#include <hip/hip_bf16.h>
#include <stdint.h>

// Problem constants
#define B_SZ   4096
#define IN_SZ  256
#define U_SZ   128
#define G_SZ   1000
#define LW_SZ  64
#define LB_SZ  32
#define K_SZ   (LW_SZ * IN_SZ)      // 16384

// GEMM tiling: out[B, U] = A[B, K] * Wf[K, U]
// A[b, l*256+i] = zw[b, l] * x[b, i]; zw applied via pk_mul on A-fragments.
#define BM     128
#define BK     64
#define KSPL   16                   // split-K over l: LSEG = 4 l's per block
#define NSTEP  16                   // 4 chunks (i) x 4 li
#define NTILE  (K_SZ / BK)          // 256 wfT k-tiles
#define CHUNK  (BK * U_SZ)          // 8192 shorts per staged tile (16 KB)

typedef __attribute__((ext_vector_type(8))) short  bf16x8;
typedef __attribute__((ext_vector_type(4))) float  f32x4;
typedef __attribute__((ext_vector_type(8))) _Float16 f16x8;
typedef __attribute__((ext_vector_type(2))) _Float16 f16x2;
typedef __attribute__((ext_vector_type(4))) _Float16 f16x4;

typedef const void __attribute__((address_space(1)))* gas_ptr;
typedef void __attribute__((address_space(3)))* las_ptr;

__device__ __forceinline__ ushort f2bf(float f) {
    unsigned u = __float_as_uint(f);
    u += 0x7fffu + ((u >> 16) & 1u);
    return (ushort)(u >> 16);
}

__device__ __forceinline__ float softplus_f(float v) {
    return fmaxf(v, 0.0f) + log1pf(__expf(-fabsf(v)));
}

// ---------------------------------------------------------------------------
// Prep (fused): blocks 0..255 convert Wf -> wfT (f16, transposed to Bs[u][k]
// layout, XOR swizzle pre-applied); blocks 256..383 convert x -> xh (f16,
// per-(mtile,chunk), swizzle pre-applied). Both staged later with linear-dest
// global_load_lds.
// ---------------------------------------------------------------------------
__global__ __launch_bounds__(256) void fmd_prep(
    const float* __restrict__ Wf, const float* __restrict__ x,
    short* __restrict__ wfT, short* __restrict__ xh)
{
    const int tid = threadIdx.x;
    if (blockIdx.x < NTILE) {
        const int t = blockIdx.x;               // k-tile 0..255
        __shared__ float lds[64 * 132];         // [kk][u], padded
        #pragma unroll
        for (int it = 0; it < 8; ++it) {
            int idx = it * 256 + tid;           // 2048 float4 slots
            int kk = idx >> 5, u4 = idx & 31;
            float4 v = *reinterpret_cast<const float4*>(&Wf[(t * 64 + kk) * U_SZ + u4 * 4]);
            *reinterpret_cast<float4*>(&lds[kk * 132 + u4 * 4]) = v;
        }
        __syncthreads();
        short* chunk = wfT + t * CHUNK;
        #pragma unroll
        for (int g = 0; g < 4; ++g) {
            int p = g * 2048 + tid * 8;
            int u = p >> 6;
            int cc = p & 63;
            int kk0 = cc ^ ((u & 7) << 3);      // swizzle bits 3..5; cc is 8-aligned
            union { _Float16 h[8]; f16x8 v; } pk;
            #pragma unroll
            for (int j = 0; j < 8; ++j)
                pk.h[j] = (_Float16)lds[(kk0 + j) * 132 + u];
            *reinterpret_cast<f16x8*>(&chunk[p]) = pk.v;
        }
    } else {
        const int bb = blockIdx.x - NTILE;      // 0..127 : (mtile, chunk)
        const int mt = bb >> 2, c = bb & 3;
        short* chunk = xh + bb * CHUNK;
        #pragma unroll
        for (int g = 0; g < 4; ++g) {
            int p = g * 2048 + tid * 8;
            int r = p >> 6;
            int cc0 = (p & 63) ^ ((r & 7) << 3);
            const float* src = &x[(mt * BM + r) * IN_SZ + c * 64 + cc0];
            float4 a = *reinterpret_cast<const float4*>(src);
            float4 b = *reinterpret_cast<const float4*>(src + 4);
            union { _Float16 h[8]; f16x8 v; } pk;
            pk.h[0] = (_Float16)a.x; pk.h[1] = (_Float16)a.y;
            pk.h[2] = (_Float16)a.z; pk.h[3] = (_Float16)a.w;
            pk.h[4] = (_Float16)b.x; pk.h[5] = (_Float16)b.y;
            pk.h[6] = (_Float16)b.z; pk.h[7] = (_Float16)b.w;
            *reinterpret_cast<f16x8*>(&chunk[p]) = pk.v;
        }
    }
}

// ---------------------------------------------------------------------------
// GEMM: grid = 32 M-tiles x KSPL = 512 blocks, 4 waves, 64x64 wave tile.
// Both operands staged via global_load_lds (zero staging VALU); zw applied
// to A-fragments in-register via packed f16 mul. 2-phase stage-ahead:
// issue next-step loads, sched_barrier, compute, one barrier per step.
// Partials (f16) written to ws slice [ks][B][U].
// ---------------------------------------------------------------------------
__global__ __launch_bounds__(256, 2) void fmd_gemm3(
    const short* __restrict__ xh,
    const short* __restrict__ wfT,
    const float* __restrict__ zw_mu,
    const float* __restrict__ zw_sigma,
    const float* __restrict__ eps_w,
    const int*   __restrict__ gid,
    _Float16*    __restrict__ part)
{
    const int tid  = threadIdx.x;
    const int lane = tid & 63;
    const int wid  = tid >> 6;
    const int wr   = wid >> 1;
    const int wc   = wid & 1;
    const int bid  = blockIdx.x;
    const int ks   = bid & (KSPL - 1);
    const int mt   = bid >> 4;
    const int m0   = mt * BM;

    __shared__ short As[2][CHUNK];   // 32 KB, x (unscaled), swizzled layout
    __shared__ short Bs[2][CHUNK];   // 32 KB, Wf^T, swizzled layout

    // --- prologue: per-lane packed zw for its 4 rows x 4 li ---
    f16x2 zwp[4][4];
    #pragma unroll
    for (int m = 0; m < 4; ++m) {
        int row = wr * 64 + m * 16 + (lane & 15);
        int b   = m0 + row;
        int g   = gid[b];
        float4 mu = *reinterpret_cast<const float4*>(&zw_mu[g * LW_SZ + ks * 4]);
        float4 sg = *reinterpret_cast<const float4*>(&zw_sigma[g * LW_SZ + ks * 4]);
        float4 ep = *reinterpret_cast<const float4*>(&eps_w[b * LW_SZ + ks * 4]);
        float v0 = mu.x + softplus_f(sg.x) * ep.x;
        float v1 = mu.y + softplus_f(sg.y) * ep.y;
        float v2 = mu.z + softplus_f(sg.z) * ep.z;
        float v3 = mu.w + softplus_f(sg.w) * ep.w;
        _Float16 h0 = (_Float16)v0, h1 = (_Float16)v1, h2 = (_Float16)v2, h3 = (_Float16)v3;
        zwp[m][0] = (f16x2){h0, h0};
        zwp[m][1] = (f16x2){h1, h1};
        zwp[m][2] = (f16x2){h2, h2};
        zwp[m][3] = (f16x2){h3, h3};
    }

    const int soff = wid * 2048 + lane * 8;    // per-thread staging offset (shorts)
    const int doff = wid * 2048;

    // prologue stages: As chunk 0, Bs tile(s=0) = ks*16 + 0
    {
        const short* sA = xh + (mt * 4 + 0) * CHUNK;
        const short* sB = wfT + (ks * 16 + 0) * CHUNK;
        #pragma unroll
        for (int j = 0; j < 4; ++j) {
            __builtin_amdgcn_global_load_lds((gas_ptr)(sA + soff + j * 512),
                                             (las_ptr)(&As[0][doff + j * 512]), 16, 0, 0);
            __builtin_amdgcn_global_load_lds((gas_ptr)(sB + soff + j * 512),
                                             (las_ptr)(&Bs[0][doff + j * 512]), 16, 0, 0);
        }
    }
    __syncthreads();

    f32x4 acc[4][4];
    #pragma unroll
    for (int m = 0; m < 4; ++m)
        #pragma unroll
        for (int n = 0; n < 4; ++n)
            acc[m][n] = (f32x4){0.f, 0.f, 0.f, 0.f};

    for (int c = 0; c < 4; ++c) {
        #pragma unroll
        for (int li = 0; li < 4; ++li) {
            const int s = c * 4 + li;
            // --- issue next-step stages (land in the other buffers) ---
            if (s < NSTEP - 1) {
                const int sn = s + 1, cn = sn >> 2, lin = sn & 3;
                const short* sB = wfT + (ks * 16 + lin * 4 + cn) * CHUNK;
                short* dB = &Bs[sn & 1][doff];
                #pragma unroll
                for (int j = 0; j < 4; ++j)
                    __builtin_amdgcn_global_load_lds((gas_ptr)(sB + soff + j * 512),
                                                     (las_ptr)(dB + j * 512), 16, 0, 0);
                if (lin == 0) {
                    const short* sA = xh + (mt * 4 + cn) * CHUNK;
                    short* dA = &As[cn & 1][doff];
                    #pragma unroll
                    for (int j = 0; j < 4; ++j)
                        __builtin_amdgcn_global_load_lds((gas_ptr)(sA + soff + j * 512),
                                                         (las_ptr)(dA + j * 512), 16, 0, 0);
                }
            }
            __builtin_amdgcn_sched_barrier(0);   // keep stage-issue before compute

            const short* Ab = As[c & 1];
            const short* Bb = Bs[s & 1];
            #pragma unroll
            for (int kb = 0; kb < 2; ++kb) {
                union { f16x8 v8; f16x2 v2[4]; } af[4], bfv[4], as_[4];
                #pragma unroll
                for (int m = 0; m < 4; ++m) {
                    int row = wr * 64 + m * 16 + (lane & 15);
                    int si = (row * BK + kb * 32 + (lane >> 4) * 8) ^ ((row & 7) << 3);
                    af[m].v8 = *reinterpret_cast<const f16x8*>(&Ab[si]);
                }
                #pragma unroll
                for (int n = 0; n < 4; ++n) {
                    int rowu = wc * 64 + n * 16 + (lane & 15);
                    int si = (rowu * BK + kb * 32 + (lane >> 4) * 8) ^ ((rowu & 7) << 3);
                    bfv[n].v8 = *reinterpret_cast<const f16x8*>(&Bb[si]);
                }
                #pragma unroll
                for (int m = 0; m < 4; ++m) {
                    #pragma unroll
                    for (int w = 0; w < 4; ++w)
                        as_[m].v2[w] = af[m].v2[w] * zwp[m][li];   // v_pk_mul_f16
                }
                #pragma unroll
                for (int m = 0; m < 4; ++m)
                    #pragma unroll
                    for (int n = 0; n < 4; ++n)
                        acc[m][n] = __builtin_amdgcn_mfma_f32_16x16x32_f16(
                            as_[m].v8, bfv[n].v8, acc[m][n], 0, 0, 0);
            }
            __syncthreads();
        }
    }

    // --- epilogue: f16 partials, slice ks ---
    _Float16* dst = part + (size_t)ks * (B_SZ * U_SZ);
    #pragma unroll
    for (int m = 0; m < 4; ++m) {
        int row0 = m0 + wr * 64 + m * 16 + ((lane >> 4) << 2);
        #pragma unroll
        for (int n = 0; n < 4; ++n) {
            int col = wc * 64 + n * 16 + (lane & 15);
            #pragma unroll
            for (int j = 0; j < 4; ++j)
                dst[(row0 + j) * U_SZ + col] = (_Float16)acc[m][n][j];
        }
    }
}

// ---------------------------------------------------------------------------
// Reduce + bias (fused): out[b,u] = sum_ks part[ks][b][u]
//                                 + sum_l (zb_mu+softplus(zb_sigma)*eps_b)[b,l]*Bf[l,u]
// Fully overwrites d_out (poison reset). One f32x4 per thread.
// ---------------------------------------------------------------------------
__global__ __launch_bounds__(256) void fmd_reduce2(
    const _Float16* __restrict__ part,
    const float* __restrict__ eps_b,
    const float* __restrict__ zb_mu,
    const float* __restrict__ zb_sigma,
    const float* __restrict__ Bf,
    const int*   __restrict__ gid,
    float*       __restrict__ out)
{
    const int tid = threadIdx.x;
    const int bid = blockIdx.x;
    const int i   = bid * 256 + tid;        // f32x4 index (131072 total)
    const int bl  = tid >> 5;               // local row 0..7
    const int u4  = tid & 31;               // float4 column

    __shared__ float zb[8][33];             // padded: avoid same-bank column
    {
        int b2 = bid * 8 + bl;
        int g  = gid[b2];
        float sg = softplus_f(zb_sigma[g * LB_SZ + u4]);
        zb[bl][u4] = zb_mu[g * LB_SZ + u4] + sg * eps_b[b2 * LB_SZ + u4];
    }
    __syncthreads();

    const f32x4* Bf4 = (const f32x4*)Bf;
    f32x4 acc = (f32x4){0.f, 0.f, 0.f, 0.f};
    #pragma unroll
    for (int l = 0; l < LB_SZ; ++l)
        acc += zb[bl][l] * Bf4[l * 32 + u4];

    #pragma unroll
    for (int ks = 0; ks < KSPL; ++ks) {
        f16x4 p = *reinterpret_cast<const f16x4*>(&part[(size_t)ks * (B_SZ * U_SZ) + (size_t)i * 4]);
        acc[0] += (float)p[0];
        acc[1] += (float)p[1];
        acc[2] += (float)p[2];
        acc[3] += (float)p[3];
    }
    ((f32x4*)out)[i] = acc;
}

// ---------------------------------------------------------------------------
// Legacy fallback (no workspace): round-1 bias + atomic GEMM (bf16)
// ---------------------------------------------------------------------------
__global__ __launch_bounds__(256) void fmd_bias(
    const float* __restrict__ eps_b,
    const float* __restrict__ zb_mu,
    const float* __restrict__ zb_sigma,
    const float* __restrict__ Bf,
    const int*   __restrict__ gid,
    float*       __restrict__ out)
{
    const int half = threadIdx.x >> 7;
    const int u    = threadIdx.x & 127;
    const int b    = blockIdx.x * 2 + half;

    __shared__ float zb[2][LB_SZ];
    if (u < LB_SZ) {
        int g = gid[b];
        float sg = softplus_f(zb_sigma[g * LB_SZ + u]);
        zb[half][u] = zb_mu[g * LB_SZ + u] + sg * eps_b[b * LB_SZ + u];
    }
    __syncthreads();

    float acc = 0.0f;
    #pragma unroll
    for (int l = 0; l < LB_SZ; ++l)
        acc += zb[half][l] * Bf[l * U_SZ + u];
    out[b * U_SZ + u] = acc;
}

__global__ __launch_bounds__(256, 2) void fmd_gemm_legacy(
    const float* __restrict__ x,
    const float* __restrict__ eps_w,
    const float* __restrict__ zw_mu,
    const float* __restrict__ zw_sigma,
    const float* __restrict__ Wf,
    const int*   __restrict__ gid,
    float*       __restrict__ out)
{
    const int tid  = threadIdx.x;
    const int lane = tid & 63;
    const int wid  = tid >> 6;
    const int wr   = wid >> 1;
    const int wc   = wid & 1;
    const int bid  = blockIdx.x;
    const int ks   = bid & (KSPL - 1);
    const int mt   = bid >> 4;
    const int m0   = mt * BM;

    __shared__ short As[BM * BK];
    __shared__ short Bs[U_SZ * BK];
    __shared__ float zw_s[BM][4];

    for (int it = tid; it < BM * 4; it += 256) {
        int r = it >> 2, lloc = it & 3;
        int b = m0 + r;
        int g = gid[b];
        int l = ks * 4 + lloc;
        float sg = softplus_f(zw_sigma[g * LW_SZ + l]);
        zw_s[r][lloc] = zw_mu[g * LW_SZ + l] + sg * eps_w[b * LW_SZ + l];
    }

    f32x4 acc[4][4];
    #pragma unroll
    for (int m = 0; m < 4; ++m)
        #pragma unroll
        for (int n = 0; n < 4; ++n)
            acc[m][n] = (f32x4){0.f, 0.f, 0.f, 0.f};

    for (int s = 0; s < NSTEP; ++s) {
        __syncthreads();
        const int li = s >> 2;
        const int i0 = (s & 3) * BK;
        const int k0 = ks * (K_SZ / KSPL) + s * BK;

        #pragma unroll
        for (int it = 0; it < 8; ++it) {
            int idx = it * 256 + tid;
            int r = idx >> 4, c4 = idx & 15;
            float4 xv = *reinterpret_cast<const float4*>(&x[(m0 + r) * IN_SZ + i0 + c4 * 4]);
            float zw = zw_s[r][li];
            ushort h0 = f2bf(xv.x * zw), h1 = f2bf(xv.y * zw);
            ushort h2 = f2bf(xv.z * zw), h3 = f2bf(xv.w * zw);
            unsigned long long pw = (unsigned long long)h0
                                  | ((unsigned long long)h1 << 16)
                                  | ((unsigned long long)h2 << 32)
                                  | ((unsigned long long)h3 << 48);
            int si = (r * BK + c4 * 4) ^ ((r & 7) << 3);
            *reinterpret_cast<unsigned long long*>(&As[si]) = pw;
        }
        #pragma unroll
        for (int it = 0; it < 4; ++it) {
            int idx = it * 256 + tid;
            int u = idx & 127, kg = idx >> 7;
            union { ushort h[8]; bf16x8 v; } pk;
            #pragma unroll
            for (int j = 0; j < 8; ++j)
                pk.h[j] = f2bf(Wf[(k0 + kg * 8 + j) * U_SZ + u]);
            int si = (u * BK + kg * 8) ^ ((u & 7) << 3);
            *reinterpret_cast<bf16x8*>(&Bs[si]) = pk.v;
        }
        __syncthreads();

        #pragma unroll
        for (int kb = 0; kb < 2; ++kb) {
            bf16x8 af[4], bfr[4];
            #pragma unroll
            for (int m = 0; m < 4; ++m) {
                int row = wr * 64 + m * 16 + (lane & 15);
                int si = (row * BK + kb * 32 + (lane >> 4) * 8) ^ ((row & 7) << 3);
                af[m] = *reinterpret_cast<const bf16x8*>(&As[si]);
            }
            #pragma unroll
            for (int n = 0; n < 4; ++n) {
                int rowu = wc * 64 + n * 16 + (lane & 15);
                int si = (rowu * BK + kb * 32 + (lane >> 4) * 8) ^ ((rowu & 7) << 3);
                bfr[n] = *reinterpret_cast<const bf16x8*>(&Bs[si]);
            }
            #pragma unroll
            for (int m = 0; m < 4; ++m)
                #pragma unroll
                for (int n = 0; n < 4; ++n)
                    acc[m][n] = __builtin_amdgcn_mfma_f32_16x16x32_bf16(af[m], bfr[n], acc[m][n], 0, 0, 0);
        }
    }

    #pragma unroll
    for (int m = 0; m < 4; ++m) {
        int row0 = m0 + wr * 64 + m * 16 + ((lane >> 4) << 2);
        #pragma unroll
        for (int n = 0; n < 4; ++n) {
            int col = wc * 64 + n * 16 + (lane & 15);
            #pragma unroll
            for (int j = 0; j < 4; ++j)
                atomicAdd(&out[(row0 + j) * U_SZ + col], acc[m][n][j]);
        }
    }
}

extern "C" void kernel_launch(void* const* d_in, const int* in_sizes, int n_in,
                              void* d_out, int out_size, void* d_ws, size_t ws_size,
                              hipStream_t stream) {
    const float* x        = (const float*)d_in[0];
    const float* eps_w    = (const float*)d_in[1];
    const float* eps_b    = (const float*)d_in[2];
    const float* zw_mu    = (const float*)d_in[3];
    const float* zw_sigma = (const float*)d_in[4];
    const float* Wf       = (const float*)d_in[5];
    const float* zb_mu    = (const float*)d_in[6];
    const float* zb_sigma = (const float*)d_in[7];
    const float* Bf       = (const float*)d_in[8];
    const int*   gid      = (const int*)d_in[9];
    float* out = (float*)d_out;

    const size_t WFT_BYTES  = (size_t)K_SZ * U_SZ * 2;            // 4 MB
    const size_t XH_OFF     = WFT_BYTES;
    const size_t XH_BYTES   = (size_t)B_SZ * IN_SZ * 2;           // 2 MB
    const size_t PART_OFF   = XH_OFF + XH_BYTES;
    const size_t PART_BYTES = (size_t)KSPL * B_SZ * U_SZ * 2;     // 16 MB

    if (ws_size >= PART_OFF + PART_BYTES) {
        short*     wfT  = (short*)d_ws;
        short*     xh   = (short*)((char*)d_ws + XH_OFF);
        _Float16*  part = (_Float16*)((char*)d_ws + PART_OFF);
        fmd_prep<<<NTILE + (B_SZ / BM) * 4, 256, 0, stream>>>(Wf, x, wfT, xh);
        fmd_gemm3<<<(B_SZ / BM) * KSPL, 256, 0, stream>>>(
            xh, wfT, zw_mu, zw_sigma, eps_w, gid, part);
        fmd_reduce2<<<(B_SZ * U_SZ) / 1024, 256, 0, stream>>>(
            part, eps_b, zb_mu, zb_sigma, Bf, gid, out);
    } else {
        fmd_bias<<<B_SZ / 2, 256, 0, stream>>>(eps_b, zb_mu, zb_sigma, Bf, gid, out);
        fmd_gemm_legacy<<<(B_SZ / BM) * KSPL, 256, 0, stream>>>(
            x, eps_w, zw_mu, zw_sigma, Wf, gid, out);
    }
}